// Round 5
// baseline (112.126 us; speedup 1.0000x reference)
//
#include <hip/hip_runtime.h>

#define L2E 1.44269504088896340736f
#define LN2 0.69314718055994530942f
#define NEGB -1e30f

typedef float f32x4 __attribute__((ext_vector_type(4)));
typedef __bf16 bf16x8 __attribute__((ext_vector_type(8)));

// problem sizes
static constexpr int NB = 64, NS = 512, NH = 768, NT = 500, NM = 8;

// workspace layout (bytes)
static constexpr size_t WT_ALL_OFF   = 0;        // 80*768 bf16   = 122880
static constexpr size_t WT_TYPE_OFF  = 122880;   // 512*768 bf16  = 786432
static constexpr size_t EM_T_OFF     = 909312;   // 512*3*64 f32  = 393216  (em_t[s][j][b])
static constexpr size_t SCORES_OFF   = 1302528;  // 64*512 f32    = 131072  (scores[b][s])
static constexpr size_t LABELS_T_OFF = 1433600;  // 512*64 i32    = 131072  (labels_t[s][b])
static constexpr size_t LEN_OFF      = 1564672;  // 64 i32
static constexpr size_t SCAL_OFF     = 3399936;  // 4 f32: [-, focal_sum, v_sum, -]
static constexpr size_t MATM_OFF     = 3400192;  // 64 chunks * 9 * 64 f32 = 147456
static constexpr size_t PSC_OFF      = 3547648;  // 64 chunks * 64 f32     = 16384

__device__ __forceinline__ unsigned short f2bf(float f) {
  unsigned u = __builtin_bit_cast(unsigned, f);
  u += 0x7FFFu + ((u >> 16) & 1u);
  return (unsigned short)(u >> 16);
}
__device__ __forceinline__ float sel3(float a, float b, float c, int i) {
  return i == 0 ? a : (i == 1 ? b : c);
}
__device__ __forceinline__ float lse3(float x, float y, float z) {
  float m = fmaxf(fmaxf(x, y), z);
  float p = exp2f((x - m) * L2E) + exp2f((y - m) * L2E) + exp2f((z - m) * L2E);
  return m + log2f(p) * LN2;
}
__device__ __forceinline__ bf16x8 pack8(float4 lo, float4 hi) {
  union { unsigned u[4]; bf16x8 v; } r;
  r.u[0] = (unsigned)f2bf(lo.x) | ((unsigned)f2bf(lo.y) << 16);
  r.u[1] = (unsigned)f2bf(lo.z) | ((unsigned)f2bf(lo.w) << 16);
  r.u[2] = (unsigned)f2bf(hi.x) | ((unsigned)f2bf(hi.y) << 16);
  r.u[3] = (unsigned)f2bf(hi.z) | ((unsigned)f2bf(hi.w) << 16);
  return r.v;
}

// ---------------- K_A: coalesced weight transposes + lengths + scal zero ---------------------
__global__ __launch_bounds__(256) void ka_prep(
    const float* __restrict__ W1, const float* __restrict__ Wpos,
    const float* __restrict__ Wtype, const int* __restrict__ amask,
    unsigned short* __restrict__ wt_all, unsigned short* __restrict__ wt_type,
    int* __restrict__ lengths, float* __restrict__ scal) {
  const int bid = blockIdx.x, t = threadIdx.x;
  if (bid < 108) {
    __shared__ float tl[64][65];
    const bool is_type = bid < 96;
    const int kt = is_type ? (bid % 12) : (bid - 96);
    const int k0 = kt * 64;
    const int n0 = is_type ? (bid / 12) * 64 : 0;
    const int ld = is_type ? 500 : 64;
    const int nlim = is_type ? 500 : 64;
    const float* src = is_type ? Wtype : W1;
    unsigned short* dst = is_type ? wt_type : wt_all;
    const int n = t & 63;
    #pragma unroll
    for (int i = 0; i < 16; ++i) {
      int k = i * 4 + (t >> 6);
      tl[k][n] = (n0 + n < nlim) ? src[(size_t)(k0 + k) * ld + n0 + n] : 0.f;
    }
    __syncthreads();
    const int k = t & 63;
    #pragma unroll
    for (int i = 0; i < 16; ++i) {
      int nn = i * 4 + (t >> 6);
      dst[(size_t)(n0 + nn) * 768 + k0 + k] = f2bf(tl[k][nn]);
    }
  } else if (bid == 108) {
    for (int idx = t; idx < 16 * 768; idx += 256) {
      int n = 64 + idx / 768, k = idx % 768;
      float v = (n < 67) ? Wpos[k * 3 + (n - 64)] : 0.f;
      wt_all[(size_t)n * 768 + k] = f2bf(v);
    }
  } else {
    __shared__ int part[256];
    int bb = t >> 2, qq = t & 3;
    const int4* mp = (const int4*)(amask + bb * 512 + qq * 128);
    int s = 0;
    #pragma unroll 8
    for (int i = 0; i < 32; ++i) { int4 v = mp[i]; s += v.x + v.y + v.z + v.w; }
    part[t] = s;
    __syncthreads();
    if (qq == 0) lengths[bb] = part[t] + part[t + 1] + part[t + 2] + part[t + 3];
    if (t == 0) { scal[1] = 0.f; scal[2] = 0.f; }
  }
}

// ---------------- K1: barrier-free [32768x768]@[768x80] bf16 MFMA, direct fragments ----------
// A fragments straight from hidden (f32 -> bf16 in-reg, zero redundancy);
// B fragments straight from L2-resident wt_all. No LDS, no __syncthreads.
__global__ __launch_bounds__(256) void k1_gemm(
    const float* __restrict__ hidden, const int* __restrict__ plab,
    const float* __restrict__ bpos, const float* __restrict__ b1,
    const float* __restrict__ W2, const float* __restrict__ b2,
    const float* __restrict__ biw, const unsigned short* __restrict__ wt_all,
    float* __restrict__ em_t, float* __restrict__ scores, int* __restrict__ labels_t) {
  const int t = threadIdx.x, w = t >> 6, l = t & 63;
  const int row0 = blockIdx.x * 64;
  const int c16 = l & 15, q = l >> 4;
  const float* aptr = hidden + (size_t)(row0 + 16 * w + c16) * 768;

  f32x4 acc[5];
  #pragma unroll
  for (int nt = 0; nt < 5; ++nt) acc[nt] = (f32x4){0.f, 0.f, 0.f, 0.f};

  #pragma unroll 2
  for (int it = 0; it < 12; ++it) {
    const int k0 = it * 64;
    const int ka0 = k0 + q * 8;          // slot for ks=0
    const int ka1 = k0 + (4 + q) * 8;    // slot for ks=1
    float4 a0lo = *(const float4*)(aptr + ka0);
    float4 a0hi = *(const float4*)(aptr + ka0 + 4);
    float4 a1lo = *(const float4*)(aptr + ka1);
    float4 a1hi = *(const float4*)(aptr + ka1 + 4);
    bf16x8 bf[2][5];
    #pragma unroll
    for (int nt = 0; nt < 5; ++nt) {
      const unsigned short* bp = wt_all + (size_t)(16 * nt + c16) * 768;
      bf[0][nt] = *(const bf16x8*)(bp + ka0);
      bf[1][nt] = *(const bf16x8*)(bp + ka1);
    }
    bf16x8 a0 = pack8(a0lo, a0hi);
    bf16x8 a1 = pack8(a1lo, a1hi);
    #pragma unroll
    for (int nt = 0; nt < 5; ++nt)
      acc[nt] = __builtin_amdgcn_mfma_f32_16x16x32_bf16(a0, bf[0][nt], acc[nt], 0, 0, 0);
    #pragma unroll
    for (int nt = 0; nt < 5; ++nt)
      acc[nt] = __builtin_amdgcn_mfma_f32_16x16x32_bf16(a1, bf[1][nt], acc[nt], 0, 0, 0);
  }

  // epilogue: D layout col = c16 (+16*nt), row = 16*w + 4*q + r
  const float bias2 = b2[0];
  #pragma unroll
  for (int r = 0; r < 4; ++r) {
    float s = 0.f;
    #pragma unroll
    for (int nt = 0; nt < 4; ++nt) {
      int c = 16 * nt + c16;
      float x = acc[nt][r] + b1[c];
      float th = 1.f - 2.f / (1.f + exp2f(x * (2.f * L2E)));
      s += th * W2[c];
    }
    #pragma unroll
    for (int off = 1; off < 16; off <<= 1) s += __shfl_xor(s, off, 64);
    if (c16 == 0) {
      int row = row0 + 16 * w + 4 * q + r;
      scores[row] = s + bias2;
    }
  }
  if (c16 < 3) {
    const float bi = biw[0];
    #pragma unroll
    for (int r = 0; r < 4; ++r) {
      int row = row0 + 16 * w + 4 * q + r;
      int bb = row >> 9, ss = row & 511;
      int lab = plab[row];
      float wgt = (lab > 0) ? 1.f + bi : 1.f;
      float ev = (acc[4][r] + bpos[c16]) * wgt;
      em_t[(ss * 3 + c16) * 64 + bb] = ev;
      if (c16 == 0) labels_t[ss * 64 + bb] = lab;
    }
  }
}

// ---------------- K_F: fused {kd: span-pool+type-GEMM+focal | k2a: CRF chunks} ---------------
// blocks 0..63  : kd, one batch each (8 spans)
// blocks 64..79 : k2a, one chunk per wave (c = (bid-64)*4 + wave)
__global__ __launch_bounds__(256) void kf_fused(
    const float* __restrict__ hidden, const float* __restrict__ scores,
    const int* __restrict__ tpos, const int* __restrict__ tlab,
    const unsigned short* __restrict__ wt_type, const float* __restrict__ btype,
    const float* __restrict__ em_t, const int* __restrict__ labels_t,
    const int* __restrict__ lengths, const float* __restrict__ trans,
    float* __restrict__ matM, float* __restrict__ psc, float* __restrict__ scal) {
  const int bid = blockIdx.x;
  const int t = threadIdx.x, w = t >> 6, l = t & 63;

  if (bid >= 64) {
    // ---------------- k2a: chunk c, lane = sequence ----------------
    const int b = l, c = (bid - 64) * 4 + w;
    float T0 = trans[0], T1 = trans[1], T2 = trans[2];
    float T3 = trans[3], T4 = trans[4], T5 = trans[5];
    float T6 = trans[6], T7 = trans[7], T8 = trans[8];
    const int L = lengths[b];
    const int s0 = 8 * c;
    int labp = labels_t[(c ? (s0 - 1) : 0) * 64 + b];

    float E0[8], E1[8], E2[8]; int LB[8];
    #pragma unroll
    for (int i = 0; i < 8; ++i) {
      E0[i] = em_t[((s0 + i) * 3 + 0) * 64 + b];
      E1[i] = em_t[((s0 + i) * 3 + 1) * 64 + b];
      E2[i] = em_t[((s0 + i) * 3 + 2) * 64 + b];
      LB[i] = labels_t[(s0 + i) * 64 + b];
    }

    float M[9];
    #pragma unroll
    for (int i = 0; i < 9; ++i) M[i] = (i == 0 || i == 4 || i == 8) ? 0.f : NEGB;
    float sc = 0.f;

    #pragma unroll
    for (int i = 0; i < 8; ++i) {
      int s = s0 + i;
      bool act = (s >= 1) && (s < L);
      float N[9];
      #pragma unroll
      for (int r = 0; r < 3; ++r) {
        float ma = M[3 * r], mb = M[3 * r + 1], mc = M[3 * r + 2];
        N[3 * r + 0] = lse3(ma + T0, mb + T3, mc + T6) + E0[i];
        N[3 * r + 1] = lse3(ma + T1, mb + T4, mc + T7) + E1[i];
        N[3 * r + 2] = lse3(ma + T2, mb + T5, mc + T8) + E2[i];
      }
      #pragma unroll
      for (int r = 0; r < 9; ++r) M[r] = act ? N[r] : M[r];
      int lab = LB[i];
      float ev = sel3(E0[i], E1[i], E2[i], lab);
      float trv = sel3(sel3(T0, T1, T2, lab),
                       sel3(T3, T4, T5, lab),
                       sel3(T6, T7, T8, lab), labp);
      sc += act ? (ev + trv) : 0.f;
      labp = lab;
    }
    #pragma unroll
    for (int i = 0; i < 9; ++i) matM[(c * 9 + i) * 64 + b] = M[i];
    psc[c * 64 + b] = sc;
    return;
  }

  // ---------------- kd: batch bid, 8 spans ----------------
  __shared__ unsigned short Apool[8][776];
  __shared__ float red[4][8][3];
  __shared__ float vl[8];
  const int b = bid;

  {
    const int sp = t >> 5;
    const int span = b * 8 + sp;
    const int st = tpos[span * 2], en = tpos[span * 2 + 1];
    const int len = (st + en > 0) ? (en - st) : 0;
    float sv[7], aw[7];
    float wm = -1e30f;
    #pragma unroll
    for (int j = 0; j < 7; ++j) {
      sv[j] = (j < len) ? scores[b * 512 + st + j] : -1e30f;
      wm = fmaxf(wm, sv[j]);
    }
    float den = 0.f;
    #pragma unroll
    for (int j = 0; j < 7; ++j) {
      aw[j] = (j < len) ? exp2f((sv[j] - wm) * L2E) : 0.f;
      den += aw[j];
    }
    float inv = (den > 0.f) ? 1.f / den : 0.f;
    #pragma unroll
    for (int j = 0; j < 7; ++j) aw[j] *= inv;

    const int h0 = (t & 31) * 24;
    float ap[24];
    #pragma unroll
    for (int i = 0; i < 24; ++i) ap[i] = 0.f;
    #pragma unroll
    for (int j = 0; j < 7; ++j) {
      if (j < len) {
        const float4* hp = (const float4*)(hidden + (size_t)(b * 512 + st + j) * 768 + h0);
        #pragma unroll
        for (int i = 0; i < 6; ++i) {
          float4 v = hp[i];
          ap[4 * i + 0] += aw[j] * v.x; ap[4 * i + 1] += aw[j] * v.y;
          ap[4 * i + 2] += aw[j] * v.z; ap[4 * i + 3] += aw[j] * v.w;
        }
      }
    }
    unsigned short* dp = &Apool[sp][h0];
    #pragma unroll
    for (int g = 0; g < 3; ++g) {
      uint4 v;
      v.x = (unsigned)f2bf(ap[8 * g + 0]) | ((unsigned)f2bf(ap[8 * g + 1]) << 16);
      v.y = (unsigned)f2bf(ap[8 * g + 2]) | ((unsigned)f2bf(ap[8 * g + 3]) << 16);
      v.z = (unsigned)f2bf(ap[8 * g + 4]) | ((unsigned)f2bf(ap[8 * g + 5]) << 16);
      v.w = (unsigned)f2bf(ap[8 * g + 6]) | ((unsigned)f2bf(ap[8 * g + 7]) << 16);
      *(uint4*)(dp + 8 * g) = v;
    }
  }
  __syncthreads();

  f32x4 acc[8];
  #pragma unroll
  for (int nt = 0; nt < 8; ++nt) acc[nt] = (f32x4){0.f, 0.f, 0.f, 0.f};
  const int arow = l & 15;
  const bf16x8 zerov = (bf16x8)(__bf16)0.f;
  for (int ks = 0; ks < 24; ++ks) {
    bf16x8 a = (arow < 8) ? *(const bf16x8*)(&Apool[arow][ks * 32 + 8 * (l >> 4)]) : zerov;
    #pragma unroll
    for (int nt = 0; nt < 8; ++nt) {
      int col = 128 * w + 16 * nt + (l & 15);
      bf16x8 bb = *(const bf16x8*)(wt_type + (size_t)col * 768 + ks * 32 + 8 * (l >> 4));
      acc[nt] = __builtin_amdgcn_mfma_f32_16x16x32_bf16(a, bb, acc[nt], 0, 0, 0);
    }
  }

  float bt[8]; bool vc[8];
  #pragma unroll
  for (int nt = 0; nt < 8; ++nt) {
    int col = 128 * w + 16 * nt + (l & 15);
    vc[nt] = col < 500;
    bt[nt] = vc[nt] ? btype[col] : 0.f;
  }
  #pragma unroll
  for (int r = 0; r < 4; ++r) {
    float lmax = -1e30f, ssum = 0.f;
    #pragma unroll
    for (int nt = 0; nt < 8; ++nt) {
      float lv = vc[nt] ? (acc[nt][r] + bt[nt]) : -1e30f;
      lmax = fmaxf(lmax, lv);
      ssum += vc[nt] ? lv : 0.f;
    }
    #pragma unroll
    for (int off = 1; off < 16; off <<= 1) lmax = fmaxf(lmax, __shfl_xor(lmax, off, 64));
    float sexp = 0.f;
    #pragma unroll
    for (int nt = 0; nt < 8; ++nt) {
      float lv = vc[nt] ? (acc[nt][r] + bt[nt]) : -1e30f;
      sexp += vc[nt] ? exp2f((lv - lmax) * L2E) : 0.f;
    }
    #pragma unroll
    for (int off = 1; off < 16; off <<= 1) {
      sexp += __shfl_xor(sexp, off, 64);
      ssum += __shfl_xor(ssum, off, 64);
    }
    if ((l & 15) == 0 && (l >> 4) < 2) {
      int row = 4 * (l >> 4) + r;
      red[w][row][0] = lmax; red[w][row][1] = sexp; red[w][row][2] = ssum;
    }
    if ((l >> 4) < 2) {
      int row = 4 * (l >> 4) + r;
      int lbl = tlab[b * 8 + row];
      if ((lbl >> 7) == w && (lbl & 15) == (l & 15)) {
        #pragma unroll
        for (int nt = 0; nt < 8; ++nt)
          if (((lbl >> 4) & 7) == nt) vl[row] = acc[nt][r] + btype[lbl];
      }
    }
  }
  __syncthreads();

  float fv = 0.f, vv = 0.f;
  if (t < 8) {
    const int row = t;
    float gm = fmaxf(fmaxf(red[0][row][0], red[1][row][0]),
                     fmaxf(red[2][row][0], red[3][row][0]));
    float sexp = 0.f, ssum = 0.f;
    #pragma unroll
    for (int i = 0; i < 4; ++i) {
      sexp += red[i][row][1] * exp2f((red[i][row][0] - gm) * L2E);
      ssum += red[i][row][2];
    }
    float logZ = gm + log2f(sexp) * LN2;
    float lp = vl[row] - logZ;
    float ce = -(0.9f * lp + 2e-4f * (ssum - 500.f * logZ));
    float pt = 0.9f * exp2f(lp * L2E) + 2e-4f;
    float focal = ce * (1.f - pt) * (1.f - pt);
    int span = b * 8 + row;
    bool valid = (tpos[span * 2] + tpos[span * 2 + 1]) > 0;
    fv = valid ? focal : 0.f;
    vv = valid ? 1.f : 0.f;
  }
  #pragma unroll
  for (int off = 1; off < 8; off <<= 1) {
    fv += __shfl_xor(fv, off, 64);
    vv += __shfl_xor(vv, off, 64);
  }
  if (t == 0) {
    atomicAdd(&scal[1], fv);
    atomicAdd(&scal[2], vv);
  }
}

// ---------------- K_E: CRF chunk-scan (4-chunk banked prefetch) + combine --------------------
__global__ __launch_bounds__(64) void k_final(
    const float* __restrict__ em_t, const int* __restrict__ labels_t,
    const int* __restrict__ lengths, const float* __restrict__ strans,
    const float* __restrict__ etrans, const float* __restrict__ matM,
    const float* __restrict__ psc, const float* __restrict__ scal,
    float* __restrict__ out) {
  const int b = threadIdx.x;
  const int L = lengths[b];
  const float st0 = strans[0], st1 = strans[1], st2 = strans[2];
  const float et0 = etrans[0], et1 = etrans[1], et2 = etrans[2];
  float e00 = em_t[0 * 64 + b], e01 = em_t[1 * 64 + b], e02 = em_t[2 * 64 + b];
  int lab0 = labels_t[b];
  float a0 = st0 + e00, a1 = st1 + e01, a2 = st2 + e02;
  float score = sel3(st0, st1, st2, lab0) + sel3(e00, e01, e02, lab0);

  float cur[4][10];
  #pragma unroll
  for (int j = 0; j < 4; ++j) {
    #pragma unroll
    for (int i = 0; i < 9; ++i) cur[j][i] = matM[(j * 9 + i) * 64 + b];
    cur[j][9] = psc[j * 64 + b];
  }

  for (int r = 0; r < 16; ++r) {
    float nxt[4][10];
    if (r < 15) {
      #pragma unroll
      for (int j = 0; j < 4; ++j) {
        int c = (r + 1) * 4 + j;
        #pragma unroll
        for (int i = 0; i < 9; ++i) nxt[j][i] = matM[(c * 9 + i) * 64 + b];
        nxt[j][9] = psc[c * 64 + b];
      }
    }
    #pragma unroll
    for (int j = 0; j < 4; ++j) {
      float n0 = lse3(a0 + cur[j][0], a1 + cur[j][3], a2 + cur[j][6]);
      float n1 = lse3(a0 + cur[j][1], a1 + cur[j][4], a2 + cur[j][7]);
      float n2 = lse3(a0 + cur[j][2], a1 + cur[j][5], a2 + cur[j][8]);
      a0 = n0; a1 = n1; a2 = n2;
      score += cur[j][9];
    }
    if (r < 15) {
      #pragma unroll
      for (int j = 0; j < 4; ++j)
        #pragma unroll
        for (int i = 0; i < 10; ++i) cur[j][i] = nxt[j][i];
    }
  }

  int last = labels_t[(L - 1) * 64 + b];
  score += sel3(et0, et1, et2, last);
  float logZ = lse3(a0 + et0, a1 + et1, a2 + et2);
  float nll = logZ - score;
  #pragma unroll
  for (int off = 1; off < 64; off <<= 1) nll += __shfl_xor(nll, off, 64);
  if (b == 0) {
    float pos = nll / 64.f;
    float type = scal[1] / fmaxf(scal[2], 1.f) * 10.f;
    out[0] = 0.6f * pos + 0.4f * type;
    out[1] = pos;
    out[2] = type;
  }
}

extern "C" void kernel_launch(void* const* d_in, const int* in_sizes, int n_in,
                              void* d_out, int out_size, void* d_ws, size_t ws_size,
                              hipStream_t stream) {
  const float* hidden = (const float*)d_in[0];
  const int*   amask  = (const int*)d_in[1];
  const int*   plab   = (const int*)d_in[2];
  const int*   tlab   = (const int*)d_in[3];
  const int*   tpos   = (const int*)d_in[4];
  const float* biw    = (const float*)d_in[5];
  const float* Wpos   = (const float*)d_in[6];
  const float* bpos   = (const float*)d_in[7];
  const float* strans = (const float*)d_in[8];
  const float* etrans = (const float*)d_in[9];
  const float* trans  = (const float*)d_in[10];
  const float* W1     = (const float*)d_in[11];
  const float* b1     = (const float*)d_in[12];
  const float* W2     = (const float*)d_in[13];
  const float* b2     = (const float*)d_in[14];
  const float* Wtype  = (const float*)d_in[15];
  const float* btype  = (const float*)d_in[16];
  float* out = (float*)d_out;
  char* ws = (char*)d_ws;

  unsigned short* wt_all  = (unsigned short*)(ws + WT_ALL_OFF);
  unsigned short* wt_type = (unsigned short*)(ws + WT_TYPE_OFF);
  float* em_t    = (float*)(ws + EM_T_OFF);
  float* scores  = (float*)(ws + SCORES_OFF);
  int*   labelsT = (int*)(ws + LABELS_T_OFF);
  int*   lengths = (int*)(ws + LEN_OFF);
  float* scal    = (float*)(ws + SCAL_OFF);
  float* matM    = (float*)(ws + MATM_OFF);
  float* psc     = (float*)(ws + PSC_OFF);

  ka_prep<<<110, 256, 0, stream>>>(W1, Wpos, Wtype, amask, wt_all, wt_type, lengths, scal);
  k1_gemm<<<512, 256, 0, stream>>>(hidden, plab, bpos, b1, W2, b2, biw, wt_all,
                                   em_t, scores, labelsT);
  kf_fused<<<80, 256, 0, stream>>>(hidden, scores, tpos, tlab, wt_type, btype,
                                   em_t, labelsT, lengths, trans, matM, psc, scal);
  k_final<<<1, 64, 0, stream>>>(em_t, labelsT, lengths, strans, etrans, matM, psc, scal, out);
}

// Round 6
// 90.143 us; speedup vs baseline: 1.2439x; 1.2439x over previous
//
#include <hip/hip_runtime.h>

#define L2E 1.44269504088896340736f
#define LN2 0.69314718055994530942f
#define NEGB -1e30f

typedef float f32x4 __attribute__((ext_vector_type(4)));
typedef __bf16 bf16x8 __attribute__((ext_vector_type(8)));

// problem sizes
static constexpr int NB = 64, NS = 512, NH = 768, NT = 500, NM = 8;

// workspace layout (bytes)
static constexpr size_t WT_ALL_OFF   = 0;        // 80*768 bf16   = 122880
static constexpr size_t WT_TYPE_OFF  = 122880;   // 512*768 bf16  = 786432
static constexpr size_t EM_T_OFF     = 909312;   // 512*3*64 f32  = 393216  (em_t[s][j][b])
static constexpr size_t SCORES_OFF   = 1302528;  // 64*512 f32    = 131072  (scores[b][s])
static constexpr size_t LABELS_T_OFF = 1433600;  // 512*64 i32    = 131072  (labels_t[s][b])
static constexpr size_t LEN_OFF      = 1564672;  // 64 i32
static constexpr size_t SCAL_OFF     = 3399936;  // 4 f32: [-, focal_sum, v_sum, -]
static constexpr size_t MATM_OFF     = 3400192;  // 64 chunks * 9 * 64 f32 = 147456
static constexpr size_t PSC_OFF      = 3547648;  // 64 chunks * 64 f32     = 16384

__device__ __forceinline__ unsigned short f2bf(float f) {
  unsigned u = __builtin_bit_cast(unsigned, f);
  u += 0x7FFFu + ((u >> 16) & 1u);
  return (unsigned short)(u >> 16);
}
__device__ __forceinline__ float sel3(float a, float b, float c, int i) {
  return i == 0 ? a : (i == 1 ? b : c);
}
__device__ __forceinline__ float lse3(float x, float y, float z) {
  float m = fmaxf(fmaxf(x, y), z);
  float p = exp2f((x - m) * L2E) + exp2f((y - m) * L2E) + exp2f((z - m) * L2E);
  return m + log2f(p) * LN2;
}
__device__ __forceinline__ bf16x8 pack8(float4 lo, float4 hi) {
  union { unsigned u[4]; bf16x8 v; } r;
  r.u[0] = (unsigned)f2bf(lo.x) | ((unsigned)f2bf(lo.y) << 16);
  r.u[1] = (unsigned)f2bf(lo.z) | ((unsigned)f2bf(lo.w) << 16);
  r.u[2] = (unsigned)f2bf(hi.x) | ((unsigned)f2bf(hi.y) << 16);
  r.u[3] = (unsigned)f2bf(hi.z) | ((unsigned)f2bf(hi.w) << 16);
  return r.v;
}
__device__ __forceinline__ void gload_lds16(const void* g, void* l) {
  __builtin_amdgcn_global_load_lds(
      (const __attribute__((address_space(1))) unsigned*)g,
      (__attribute__((address_space(3))) unsigned*)l, 16, 0, 0);
}

// ---------------- K_A: coalesced weight transposes + lengths + scal zero ---------------------
__global__ __launch_bounds__(256) void ka_prep(
    const float* __restrict__ W1, const float* __restrict__ Wpos,
    const float* __restrict__ Wtype, const int* __restrict__ amask,
    unsigned short* __restrict__ wt_all, unsigned short* __restrict__ wt_type,
    int* __restrict__ lengths, float* __restrict__ scal) {
  const int bid = blockIdx.x, t = threadIdx.x;
  if (bid < 108) {
    __shared__ float tl[64][65];
    const bool is_type = bid < 96;
    const int kt = is_type ? (bid % 12) : (bid - 96);
    const int k0 = kt * 64;
    const int n0 = is_type ? (bid / 12) * 64 : 0;
    const int ld = is_type ? 500 : 64;
    const int nlim = is_type ? 500 : 64;
    const float* src = is_type ? Wtype : W1;
    unsigned short* dst = is_type ? wt_type : wt_all;
    const int n = t & 63;
    #pragma unroll
    for (int i = 0; i < 16; ++i) {
      int k = i * 4 + (t >> 6);
      tl[k][n] = (n0 + n < nlim) ? src[(size_t)(k0 + k) * ld + n0 + n] : 0.f;
    }
    __syncthreads();
    const int k = t & 63;
    #pragma unroll
    for (int i = 0; i < 16; ++i) {
      int nn = i * 4 + (t >> 6);
      dst[(size_t)(n0 + nn) * 768 + k0 + k] = f2bf(tl[k][nn]);
    }
  } else if (bid == 108) {
    for (int idx = t; idx < 16 * 768; idx += 256) {
      int n = 64 + idx / 768, k = idx % 768;
      float v = (n < 67) ? Wpos[k * 3 + (n - 64)] : 0.f;
      wt_all[(size_t)n * 768 + k] = f2bf(v);
    }
  } else {
    __shared__ int part[256];
    int bb = t >> 2, qq = t & 3;
    const int4* mp = (const int4*)(amask + bb * 512 + qq * 128);
    int s = 0;
    #pragma unroll 8
    for (int i = 0; i < 32; ++i) { int4 v = mp[i]; s += v.x + v.y + v.z + v.w; }
    part[t] = s;
    __syncthreads();
    if (qq == 0) lengths[bb] = part[t] + part[t + 1] + part[t + 2] + part[t + 3];
    if (t == 0) { scal[1] = 0.f; scal[2] = 0.f; }
  }
}

// ---------------- K1: [32768x768]@[768x80] bf16 MFMA, global_load_lds dbuf + counted vmcnt ----
// A staged raw f32 (16KB/chunk), B bf16 (12KB padded). XOR-swizzle: stored_slot = slot^(row&7),
// realized by inverse-swizzling the per-lane GLOBAL source (LDS dest stays linear).
__global__ __launch_bounds__(256) void k1_gemm(
    const float* __restrict__ hidden, const int* __restrict__ plab,
    const float* __restrict__ bpos, const float* __restrict__ b1,
    const float* __restrict__ W2, const float* __restrict__ b2,
    const float* __restrict__ biw, const unsigned short* __restrict__ wt_all,
    float* __restrict__ em_t, float* __restrict__ scores, int* __restrict__ labels_t) {
  __shared__ uint4 As[2][1024];   // [64 rows][16 slots of 16B] f32, swizzled
  __shared__ uint4 Bs[2][768];    // [96 rows][8 slots of 16B] bf16, swizzled (rows>=80 pad)
  const int t = threadIdx.x, w = t >> 6, l = t & 63;
  const int row0 = blockIdx.x * 64;
  const int c16 = l & 15, q = l >> 4, r7 = c16 & 7;

  f32x4 acc[5];
  #pragma unroll
  for (int nt = 0; nt < 5; ++nt) acc[nt] = (f32x4){0.f, 0.f, 0.f, 0.f};

  // stage chunk it into buffer bi: 4 A-DMA + 3 B-DMA per thread (uniform per wave)
  auto stage = [&](int bi, int it) {
    const int k0 = it * 64;
    #pragma unroll
    for (int u = 0; u < 4; ++u) {
      int i = w * 256 + u * 64 + l;                 // A slot index 0..1023
      int row = i >> 4;
      int s = (i & 15) ^ (row & 7);
      gload_lds16(hidden + (size_t)(row0 + row) * 768 + k0 + 4 * s,
                  (void*)(As[bi] + (w * 256 + u * 64)));
    }
    #pragma unroll
    for (int u = 0; u < 3; ++u) {
      int i = w * 192 + u * 64 + l;                 // B slot index 0..767
      int row = i >> 3;
      int s = (i & 7) ^ (row & 7);
      gload_lds16(wt_all + (size_t)row * 768 + k0 + 8 * s,
                  (void*)(Bs[bi] + (w * 192 + u * 64)));
    }
  };

  stage(0, 0);
  for (int it = 0; it < 12; ++it) {
    if (it < 11) stage((it + 1) & 1, it + 1);
    if (it < 11) asm volatile("s_waitcnt vmcnt(7)" ::: "memory");
    else         asm volatile("s_waitcnt vmcnt(0)" ::: "memory");
    __builtin_amdgcn_s_barrier();
    __builtin_amdgcn_sched_barrier(0);

    const char* Ab = (const char*)As[it & 1];
    const char* Bb = (const char*)Bs[it & 1];
    const int arow = 16 * w + c16;
    float4 a00 = *(const float4*)(Ab + arow * 256 + (((2 * q + 0) ^ r7) << 4));
    float4 a01 = *(const float4*)(Ab + arow * 256 + (((2 * q + 1) ^ r7) << 4));
    float4 a10 = *(const float4*)(Ab + arow * 256 + (((8 + 2 * q) ^ r7) << 4));
    float4 a11 = *(const float4*)(Ab + arow * 256 + (((9 + 2 * q) ^ r7) << 4));
    bf16x8 bf0[5], bf1[5];
    #pragma unroll
    for (int nt = 0; nt < 5; ++nt) {
      const char* bp = Bb + (16 * nt + c16) * 128;
      bf0[nt] = *(const bf16x8*)(bp + (((0 + q) ^ r7) << 4));
      bf1[nt] = *(const bf16x8*)(bp + (((4 + q) ^ r7) << 4));
    }
    bf16x8 a0 = pack8(a00, a01);
    bf16x8 a1 = pack8(a10, a11);
    #pragma unroll
    for (int nt = 0; nt < 5; ++nt)
      acc[nt] = __builtin_amdgcn_mfma_f32_16x16x32_bf16(a0, bf0[nt], acc[nt], 0, 0, 0);
    #pragma unroll
    for (int nt = 0; nt < 5; ++nt)
      acc[nt] = __builtin_amdgcn_mfma_f32_16x16x32_bf16(a1, bf1[nt], acc[nt], 0, 0, 0);

    asm volatile("s_waitcnt lgkmcnt(0)" ::: "memory");
    __builtin_amdgcn_sched_barrier(0);
    __builtin_amdgcn_s_barrier();
  }

  // epilogue: D layout col = c16 (+16*nt), row = 16*w + 4*q + r
  const float bias2 = b2[0];
  #pragma unroll
  for (int r = 0; r < 4; ++r) {
    float s = 0.f;
    #pragma unroll
    for (int nt = 0; nt < 4; ++nt) {
      int c = 16 * nt + c16;
      float x = acc[nt][r] + b1[c];
      float th = 1.f - 2.f / (1.f + exp2f(x * (2.f * L2E)));
      s += th * W2[c];
    }
    #pragma unroll
    for (int off = 1; off < 16; off <<= 1) s += __shfl_xor(s, off, 64);
    if (c16 == 0) {
      int row = row0 + 16 * w + 4 * q + r;
      scores[row] = s + bias2;
    }
  }
  if (c16 < 3) {
    const float bi = biw[0];
    #pragma unroll
    for (int r = 0; r < 4; ++r) {
      int row = row0 + 16 * w + 4 * q + r;
      int bb = row >> 9, ss = row & 511;
      int lab = plab[row];
      float wgt = (lab > 0) ? 1.f + bi : 1.f;
      float ev = (acc[4][r] + bpos[c16]) * wgt;
      em_t[(ss * 3 + c16) * 64 + bb] = ev;
      if (c16 == 0) labels_t[ss * 64 + bb] = lab;
    }
  }
}

// ---------------- K_F: fused {kd: span-pool+type-GEMM+focal | k2a: CRF chunks} ---------------
__global__ __launch_bounds__(256) void kf_fused(
    const float* __restrict__ hidden, const float* __restrict__ scores,
    const int* __restrict__ tpos, const int* __restrict__ tlab,
    const unsigned short* __restrict__ wt_type, const float* __restrict__ btype,
    const float* __restrict__ em_t, const int* __restrict__ labels_t,
    const int* __restrict__ lengths, const float* __restrict__ trans,
    float* __restrict__ matM, float* __restrict__ psc, float* __restrict__ scal) {
  const int bid = blockIdx.x;
  const int t = threadIdx.x, w = t >> 6, l = t & 63;

  if (bid >= 64) {
    // ---------------- k2a: chunk c, lane = sequence ----------------
    const int b = l, c = (bid - 64) * 4 + w;
    float T0 = trans[0], T1 = trans[1], T2 = trans[2];
    float T3 = trans[3], T4 = trans[4], T5 = trans[5];
    float T6 = trans[6], T7 = trans[7], T8 = trans[8];
    const int L = lengths[b];
    const int s0 = 8 * c;
    int labp = labels_t[(c ? (s0 - 1) : 0) * 64 + b];

    float E0[8], E1[8], E2[8]; int LB[8];
    #pragma unroll
    for (int i = 0; i < 8; ++i) {
      E0[i] = em_t[((s0 + i) * 3 + 0) * 64 + b];
      E1[i] = em_t[((s0 + i) * 3 + 1) * 64 + b];
      E2[i] = em_t[((s0 + i) * 3 + 2) * 64 + b];
      LB[i] = labels_t[(s0 + i) * 64 + b];
    }

    float M[9];
    #pragma unroll
    for (int i = 0; i < 9; ++i) M[i] = (i == 0 || i == 4 || i == 8) ? 0.f : NEGB;
    float sc = 0.f;

    #pragma unroll
    for (int i = 0; i < 8; ++i) {
      int s = s0 + i;
      bool act = (s >= 1) && (s < L);
      float N[9];
      #pragma unroll
      for (int r = 0; r < 3; ++r) {
        float ma = M[3 * r], mb = M[3 * r + 1], mc = M[3 * r + 2];
        N[3 * r + 0] = lse3(ma + T0, mb + T3, mc + T6) + E0[i];
        N[3 * r + 1] = lse3(ma + T1, mb + T4, mc + T7) + E1[i];
        N[3 * r + 2] = lse3(ma + T2, mb + T5, mc + T8) + E2[i];
      }
      #pragma unroll
      for (int r = 0; r < 9; ++r) M[r] = act ? N[r] : M[r];
      int lab = LB[i];
      float ev = sel3(E0[i], E1[i], E2[i], lab);
      float trv = sel3(sel3(T0, T1, T2, lab),
                       sel3(T3, T4, T5, lab),
                       sel3(T6, T7, T8, lab), labp);
      sc += act ? (ev + trv) : 0.f;
      labp = lab;
    }
    #pragma unroll
    for (int i = 0; i < 9; ++i) matM[(c * 9 + i) * 64 + b] = M[i];
    psc[c * 64 + b] = sc;
    return;
  }

  // ---------------- kd: batch bid, 8 spans ----------------
  __shared__ unsigned short Apool[8][776];
  __shared__ float red[4][8][3];
  __shared__ float vl[8];
  const int b = bid;

  {
    const int sp = t >> 5;
    const int span = b * 8 + sp;
    const int st = tpos[span * 2], en = tpos[span * 2 + 1];
    const int len = (st + en > 0) ? (en - st) : 0;
    float sv[7], aw[7];
    float wm = -1e30f;
    #pragma unroll
    for (int j = 0; j < 7; ++j) {
      sv[j] = (j < len) ? scores[b * 512 + st + j] : -1e30f;
      wm = fmaxf(wm, sv[j]);
    }
    float den = 0.f;
    #pragma unroll
    for (int j = 0; j < 7; ++j) {
      aw[j] = (j < len) ? exp2f((sv[j] - wm) * L2E) : 0.f;
      den += aw[j];
    }
    float inv = (den > 0.f) ? 1.f / den : 0.f;
    #pragma unroll
    for (int j = 0; j < 7; ++j) aw[j] *= inv;

    const int h0 = (t & 31) * 24;
    float ap[24];
    #pragma unroll
    for (int i = 0; i < 24; ++i) ap[i] = 0.f;
    #pragma unroll
    for (int j = 0; j < 7; ++j) {
      if (j < len) {
        const float4* hp = (const float4*)(hidden + (size_t)(b * 512 + st + j) * 768 + h0);
        #pragma unroll
        for (int i = 0; i < 6; ++i) {
          float4 v = hp[i];
          ap[4 * i + 0] += aw[j] * v.x; ap[4 * i + 1] += aw[j] * v.y;
          ap[4 * i + 2] += aw[j] * v.z; ap[4 * i + 3] += aw[j] * v.w;
        }
      }
    }
    unsigned short* dp = &Apool[sp][h0];
    #pragma unroll
    for (int g = 0; g < 3; ++g) {
      uint4 v;
      v.x = (unsigned)f2bf(ap[8 * g + 0]) | ((unsigned)f2bf(ap[8 * g + 1]) << 16);
      v.y = (unsigned)f2bf(ap[8 * g + 2]) | ((unsigned)f2bf(ap[8 * g + 3]) << 16);
      v.z = (unsigned)f2bf(ap[8 * g + 4]) | ((unsigned)f2bf(ap[8 * g + 5]) << 16);
      v.w = (unsigned)f2bf(ap[8 * g + 6]) | ((unsigned)f2bf(ap[8 * g + 7]) << 16);
      *(uint4*)(dp + 8 * g) = v;
    }
  }
  __syncthreads();

  f32x4 acc[8];
  #pragma unroll
  for (int nt = 0; nt < 8; ++nt) acc[nt] = (f32x4){0.f, 0.f, 0.f, 0.f};
  const int arow = l & 15;
  const bf16x8 zerov = (bf16x8)(__bf16)0.f;
  for (int ks = 0; ks < 24; ++ks) {
    bf16x8 a = (arow < 8) ? *(const bf16x8*)(&Apool[arow][ks * 32 + 8 * (l >> 4)]) : zerov;
    #pragma unroll
    for (int nt = 0; nt < 8; ++nt) {
      int col = 128 * w + 16 * nt + (l & 15);
      bf16x8 bb = *(const bf16x8*)(wt_type + (size_t)col * 768 + ks * 32 + 8 * (l >> 4));
      acc[nt] = __builtin_amdgcn_mfma_f32_16x16x32_bf16(a, bb, acc[nt], 0, 0, 0);
    }
  }

  float bt[8]; bool vc[8];
  #pragma unroll
  for (int nt = 0; nt < 8; ++nt) {
    int col = 128 * w + 16 * nt + (l & 15);
    vc[nt] = col < 500;
    bt[nt] = vc[nt] ? btype[col] : 0.f;
  }
  #pragma unroll
  for (int r = 0; r < 4; ++r) {
    float lmax = -1e30f, ssum = 0.f;
    #pragma unroll
    for (int nt = 0; nt < 8; ++nt) {
      float lv = vc[nt] ? (acc[nt][r] + bt[nt]) : -1e30f;
      lmax = fmaxf(lmax, lv);
      ssum += vc[nt] ? lv : 0.f;
    }
    #pragma unroll
    for (int off = 1; off < 16; off <<= 1) lmax = fmaxf(lmax, __shfl_xor(lmax, off, 64));
    float sexp = 0.f;
    #pragma unroll
    for (int nt = 0; nt < 8; ++nt) {
      float lv = vc[nt] ? (acc[nt][r] + bt[nt]) : -1e30f;
      sexp += vc[nt] ? exp2f((lv - lmax) * L2E) : 0.f;
    }
    #pragma unroll
    for (int off = 1; off < 16; off <<= 1) {
      sexp += __shfl_xor(sexp, off, 64);
      ssum += __shfl_xor(ssum, off, 64);
    }
    if ((l & 15) == 0 && (l >> 4) < 2) {
      int row = 4 * (l >> 4) + r;
      red[w][row][0] = lmax; red[w][row][1] = sexp; red[w][row][2] = ssum;
    }
    if ((l >> 4) < 2) {
      int row = 4 * (l >> 4) + r;
      int lbl = tlab[b * 8 + row];
      if ((lbl >> 7) == w && (lbl & 15) == (l & 15)) {
        #pragma unroll
        for (int nt = 0; nt < 8; ++nt)
          if (((lbl >> 4) & 7) == nt) vl[row] = acc[nt][r] + btype[lbl];
      }
    }
  }
  __syncthreads();

  float fv = 0.f, vv = 0.f;
  if (t < 8) {
    const int row = t;
    float gm = fmaxf(fmaxf(red[0][row][0], red[1][row][0]),
                     fmaxf(red[2][row][0], red[3][row][0]));
    float sexp = 0.f, ssum = 0.f;
    #pragma unroll
    for (int i = 0; i < 4; ++i) {
      sexp += red[i][row][1] * exp2f((red[i][row][0] - gm) * L2E);
      ssum += red[i][row][2];
    }
    float logZ = gm + log2f(sexp) * LN2;
    float lp = vl[row] - logZ;
    float ce = -(0.9f * lp + 2e-4f * (ssum - 500.f * logZ));
    float pt = 0.9f * exp2f(lp * L2E) + 2e-4f;
    float focal = ce * (1.f - pt) * (1.f - pt);
    int span = b * 8 + row;
    bool valid = (tpos[span * 2] + tpos[span * 2 + 1]) > 0;
    fv = valid ? focal : 0.f;
    vv = valid ? 1.f : 0.f;
  }
  #pragma unroll
  for (int off = 1; off < 8; off <<= 1) {
    fv += __shfl_xor(fv, off, 64);
    vv += __shfl_xor(vv, off, 64);
  }
  if (t == 0) {
    atomicAdd(&scal[1], fv);
    atomicAdd(&scal[2], vv);
  }
}

// ---------------- K_E: CRF chunk-scan (4-chunk banked prefetch) + combine --------------------
__global__ __launch_bounds__(64) void k_final(
    const float* __restrict__ em_t, const int* __restrict__ labels_t,
    const int* __restrict__ lengths, const float* __restrict__ strans,
    const float* __restrict__ etrans, const float* __restrict__ matM,
    const float* __restrict__ psc, const float* __restrict__ scal,
    float* __restrict__ out) {
  const int b = threadIdx.x;
  const int L = lengths[b];
  const float st0 = strans[0], st1 = strans[1], st2 = strans[2];
  const float et0 = etrans[0], et1 = etrans[1], et2 = etrans[2];
  float e00 = em_t[0 * 64 + b], e01 = em_t[1 * 64 + b], e02 = em_t[2 * 64 + b];
  int lab0 = labels_t[b];
  float a0 = st0 + e00, a1 = st1 + e01, a2 = st2 + e02;
  float score = sel3(st0, st1, st2, lab0) + sel3(e00, e01, e02, lab0);

  float cur[4][10];
  #pragma unroll
  for (int j = 0; j < 4; ++j) {
    #pragma unroll
    for (int i = 0; i < 9; ++i) cur[j][i] = matM[(j * 9 + i) * 64 + b];
    cur[j][9] = psc[j * 64 + b];
  }

  for (int r = 0; r < 16; ++r) {
    float nxt[4][10];
    if (r < 15) {
      #pragma unroll
      for (int j = 0; j < 4; ++j) {
        int c = (r + 1) * 4 + j;
        #pragma unroll
        for (int i = 0; i < 9; ++i) nxt[j][i] = matM[(c * 9 + i) * 64 + b];
        nxt[j][9] = psc[c * 64 + b];
      }
    }
    #pragma unroll
    for (int j = 0; j < 4; ++j) {
      float n0 = lse3(a0 + cur[j][0], a1 + cur[j][3], a2 + cur[j][6]);
      float n1 = lse3(a0 + cur[j][1], a1 + cur[j][4], a2 + cur[j][7]);
      float n2 = lse3(a0 + cur[j][2], a1 + cur[j][5], a2 + cur[j][8]);
      a0 = n0; a1 = n1; a2 = n2;
      score += cur[j][9];
    }
    if (r < 15) {
      #pragma unroll
      for (int j = 0; j < 4; ++j)
        #pragma unroll
        for (int i = 0; i < 10; ++i) cur[j][i] = nxt[j][i];
    }
  }

  int last = labels_t[(L - 1) * 64 + b];
  score += sel3(et0, et1, et2, last);
  float logZ = lse3(a0 + et0, a1 + et1, a2 + et2);
  float nll = logZ - score;
  #pragma unroll
  for (int off = 1; off < 64; off <<= 1) nll += __shfl_xor(nll, off, 64);
  if (b == 0) {
    float pos = nll / 64.f;
    float type = scal[1] / fmaxf(scal[2], 1.f) * 10.f;
    out[0] = 0.6f * pos + 0.4f * type;
    out[1] = pos;
    out[2] = type;
  }
}

extern "C" void kernel_launch(void* const* d_in, const int* in_sizes, int n_in,
                              void* d_out, int out_size, void* d_ws, size_t ws_size,
                              hipStream_t stream) {
  const float* hidden = (const float*)d_in[0];
  const int*   amask  = (const int*)d_in[1];
  const int*   plab   = (const int*)d_in[2];
  const int*   tlab   = (const int*)d_in[3];
  const int*   tpos   = (const int*)d_in[4];
  const float* biw    = (const float*)d_in[5];
  const float* Wpos   = (const float*)d_in[6];
  const float* bpos   = (const float*)d_in[7];
  const float* strans = (const float*)d_in[8];
  const float* etrans = (const float*)d_in[9];
  const float* trans  = (const float*)d_in[10];
  const float* W1     = (const float*)d_in[11];
  const float* b1     = (const float*)d_in[12];
  const float* W2     = (const float*)d_in[13];
  const float* b2     = (const float*)d_in[14];
  const float* Wtype  = (const float*)d_in[15];
  const float* btype  = (const float*)d_in[16];
  float* out = (float*)d_out;
  char* ws = (char*)d_ws;

  unsigned short* wt_all  = (unsigned short*)(ws + WT_ALL_OFF);
  unsigned short* wt_type = (unsigned short*)(ws + WT_TYPE_OFF);
  float* em_t    = (float*)(ws + EM_T_OFF);
  float* scores  = (float*)(ws + SCORES_OFF);
  int*   labelsT = (int*)(ws + LABELS_T_OFF);
  int*   lengths = (int*)(ws + LEN_OFF);
  float* scal    = (float*)(ws + SCAL_OFF);
  float* matM    = (float*)(ws + MATM_OFF);
  float* psc     = (float*)(ws + PSC_OFF);

  ka_prep<<<110, 256, 0, stream>>>(W1, Wpos, Wtype, amask, wt_all, wt_type, lengths, scal);
  k1_gemm<<<512, 256, 0, stream>>>(hidden, plab, bpos, b1, W2, b2, biw, wt_all,
                                   em_t, scores, labelsT);
  kf_fused<<<80, 256, 0, stream>>>(hidden, scores, tpos, tlab, wt_type, btype,
                                   em_t, labelsT, lengths, trans, matM, psc, scal);
  k_final<<<1, 64, 0, stream>>>(em_t, labelsT, lengths, strans, etrans, matM, psc, scal, out);
}

// Round 7
// 89.044 us; speedup vs baseline: 1.2592x; 1.0123x over previous
//
#include <hip/hip_runtime.h>

#define L2E 1.44269504088896340736f
#define LN2 0.69314718055994530942f
#define NEGB -1e30f

typedef float f32x4 __attribute__((ext_vector_type(4)));
typedef __bf16 bf16x8 __attribute__((ext_vector_type(8)));

// problem sizes
static constexpr int NB = 64, NS = 512, NH = 768, NT = 500, NM = 8;

// workspace layout (bytes)
static constexpr size_t WT_ALL_OFF   = 0;        // 80*768 bf16   = 122880
static constexpr size_t WT_TYPE_OFF  = 122880;   // 512*768 bf16  = 786432
static constexpr size_t EM_T_OFF     = 909312;   // 512*3*64 f32  = 393216  (em_t[s][j][b])
static constexpr size_t SCORES_OFF   = 1302528;  // 64*512 f32    = 131072  (scores[b][s])
static constexpr size_t LABELS_T_OFF = 1433600;  // 512*64 i32    = 131072  (labels_t[s][b])
static constexpr size_t LEN_OFF      = 1564672;  // 64 i32
static constexpr size_t SCAL_OFF     = 3399936;  // 4 f32: [-, focal_sum, v_sum, block_counter]
static constexpr size_t MATM_OFF     = 3400192;  // 64 chunks * 9 * 64 f32 = 147456
static constexpr size_t PSC_OFF      = 3547648;  // 64 chunks * 64 f32     = 16384

__device__ __forceinline__ unsigned short f2bf(float f) {
  unsigned u = __builtin_bit_cast(unsigned, f);
  u += 0x7FFFu + ((u >> 16) & 1u);
  return (unsigned short)(u >> 16);
}
__device__ __forceinline__ float sel3(float a, float b, float c, int i) {
  return i == 0 ? a : (i == 1 ? b : c);
}
__device__ __forceinline__ float lse3(float x, float y, float z) {
  float m = fmaxf(fmaxf(x, y), z);
  float p = exp2f((x - m) * L2E) + exp2f((y - m) * L2E) + exp2f((z - m) * L2E);
  return m + log2f(p) * LN2;
}
__device__ __forceinline__ bf16x8 pack8(float4 lo, float4 hi) {
  union { unsigned u[4]; bf16x8 v; } r;
  asm("v_cvt_pk_bf16_f32 %0, %1, %2" : "=v"(r.u[0]) : "v"(lo.x), "v"(lo.y));
  asm("v_cvt_pk_bf16_f32 %0, %1, %2" : "=v"(r.u[1]) : "v"(lo.z), "v"(lo.w));
  asm("v_cvt_pk_bf16_f32 %0, %1, %2" : "=v"(r.u[2]) : "v"(hi.x), "v"(hi.y));
  asm("v_cvt_pk_bf16_f32 %0, %1, %2" : "=v"(r.u[3]) : "v"(hi.z), "v"(hi.w));
  return r.v;
}
__device__ __forceinline__ void gload_lds16(const void* g, void* l) {
  __builtin_amdgcn_global_load_lds(
      (const __attribute__((address_space(1))) unsigned*)g,
      (__attribute__((address_space(3))) unsigned*)l, 16, 0, 0);
}

// ---------------- K_A: coalesced weight transposes + lengths + scal/counter zero -------------
__global__ __launch_bounds__(256) void ka_prep(
    const float* __restrict__ W1, const float* __restrict__ Wpos,
    const float* __restrict__ Wtype, const int* __restrict__ amask,
    unsigned short* __restrict__ wt_all, unsigned short* __restrict__ wt_type,
    int* __restrict__ lengths, float* __restrict__ scal) {
  const int bid = blockIdx.x, t = threadIdx.x;
  if (bid < 108) {
    __shared__ float tl[64][65];
    const bool is_type = bid < 96;
    const int kt = is_type ? (bid % 12) : (bid - 96);
    const int k0 = kt * 64;
    const int n0 = is_type ? (bid / 12) * 64 : 0;
    const int ld = is_type ? 500 : 64;
    const int nlim = is_type ? 500 : 64;
    const float* src = is_type ? Wtype : W1;
    unsigned short* dst = is_type ? wt_type : wt_all;
    const int n = t & 63;
    #pragma unroll
    for (int i = 0; i < 16; ++i) {
      int k = i * 4 + (t >> 6);
      tl[k][n] = (n0 + n < nlim) ? src[(size_t)(k0 + k) * ld + n0 + n] : 0.f;
    }
    __syncthreads();
    const int k = t & 63;
    #pragma unroll
    for (int i = 0; i < 16; ++i) {
      int nn = i * 4 + (t >> 6);
      dst[(size_t)(n0 + nn) * 768 + k0 + k] = f2bf(tl[k][nn]);
    }
  } else if (bid == 108) {
    for (int idx = t; idx < 16 * 768; idx += 256) {
      int n = 64 + idx / 768, k = idx % 768;
      float v = (n < 67) ? Wpos[k * 3 + (n - 64)] : 0.f;
      wt_all[(size_t)n * 768 + k] = f2bf(v);
    }
  } else {
    __shared__ int part[256];
    int bb = t >> 2, qq = t & 3;
    const int4* mp = (const int4*)(amask + bb * 512 + qq * 128);
    int s = 0;
    #pragma unroll 8
    for (int i = 0; i < 32; ++i) { int4 v = mp[i]; s += v.x + v.y + v.z + v.w; }
    part[t] = s;
    __syncthreads();
    if (qq == 0) lengths[bb] = part[t] + part[t + 1] + part[t + 2] + part[t + 3];
    if (t == 0) { scal[1] = 0.f; scal[2] = 0.f; scal[3] = 0.f; }
  }
}

// ---------------- K1: [32768x768]@[768x80] bf16 MFMA, 4-buf 2-deep DMA pipeline --------------
// K-chunk 32. A: 64r x 8 slots f32, swz slot^(row&7). B: 128r x 4 slots bf16, swz slot^((row>>1)&3).
// One barrier per iteration (4 buffers make write-vs-read skew safe); vmcnt(8) counted wait.
__global__ __launch_bounds__(256) void k1_gemm(
    const float* __restrict__ hidden, const int* __restrict__ plab,
    const float* __restrict__ bpos, const float* __restrict__ b1,
    const float* __restrict__ W2, const float* __restrict__ b2,
    const float* __restrict__ biw, const unsigned short* __restrict__ wt_all,
    float* __restrict__ em_t, float* __restrict__ scores, int* __restrict__ labels_t) {
  __shared__ uint4 As[4][512];   // 8 KB per buf
  __shared__ uint4 Bs[4][512];   // 8 KB per buf (rows 80..127 garbage, never used)
  const int t = threadIdx.x, w = t >> 6, l = t & 63;
  const int row0 = blockIdx.x * 64;
  const int c16 = l & 15, q = l >> 4;

  f32x4 acc[5];
  #pragma unroll
  for (int nt = 0; nt < 5; ++nt) acc[nt] = (f32x4){0.f, 0.f, 0.f, 0.f};

  // stage chunk it: 2 A-DMA + 2 B-DMA per thread (uniform per wave)
  auto stage = [&](int it) {
    const int bi = it & 3;
    const int k0 = it * 32;
    #pragma unroll
    for (int u = 0; u < 2; ++u) {
      int i = w * 128 + u * 64 + l;          // A slot 0..511
      int row = i >> 3;
      int ss = (i & 7) ^ (row & 7);
      gload_lds16(hidden + (size_t)(row0 + row) * 768 + k0 + 4 * ss,
                  (void*)(As[bi] + (w * 128 + u * 64)));
    }
    #pragma unroll
    for (int u = 0; u < 2; ++u) {
      int i = w * 128 + u * 64 + l;          // B slot 0..511
      int row = i >> 2;
      int ss = (i & 3) ^ ((row >> 1) & 3);
      gload_lds16(wt_all + (size_t)row * 768 + k0 + 8 * ss,
                  (void*)(Bs[bi] + (w * 128 + u * 64)));
    }
  };

  stage(0); stage(1);
  for (int it = 0; it < 24; ++it) {
    if (it < 22) stage(it + 2);
    if (it < 22)      asm volatile("s_waitcnt vmcnt(8)" ::: "memory");
    else if (it == 22) asm volatile("s_waitcnt vmcnt(4)" ::: "memory");
    else               asm volatile("s_waitcnt vmcnt(0)" ::: "memory");
    __builtin_amdgcn_s_barrier();
    __builtin_amdgcn_sched_barrier(0);

    const int bi = it & 3;
    const char* Ab = (const char*)As[bi];
    const char* Bb = (const char*)Bs[bi];
    const int arow = 16 * w + c16, r7 = arow & 7;
    float4 alo = *(const float4*)(Ab + arow * 128 + (((2 * q + 0) ^ r7) << 4));
    float4 ahi = *(const float4*)(Ab + arow * 128 + (((2 * q + 1) ^ r7) << 4));
    bf16x8 a = pack8(alo, ahi);
    #pragma unroll
    for (int nt = 0; nt < 5; ++nt) {
      const int brow = 16 * nt + c16;
      bf16x8 b = *(const bf16x8*)(Bb + brow * 64 + ((q ^ ((brow >> 1) & 3)) << 4));
      acc[nt] = __builtin_amdgcn_mfma_f32_16x16x32_bf16(a, b, acc[nt], 0, 0, 0);
    }
  }

  // epilogue: D layout col = c16 (+16*nt), row = 16*w + 4*q + r
  const float bias2 = b2[0];
  #pragma unroll
  for (int r = 0; r < 4; ++r) {
    float s = 0.f;
    #pragma unroll
    for (int nt = 0; nt < 4; ++nt) {
      int c = 16 * nt + c16;
      float x = acc[nt][r] + b1[c];
      float th = 1.f - 2.f / (1.f + exp2f(x * (2.f * L2E)));
      s += th * W2[c];
    }
    #pragma unroll
    for (int off = 1; off < 16; off <<= 1) s += __shfl_xor(s, off, 64);
    if (c16 == 0) {
      int row = row0 + 16 * w + 4 * q + r;
      scores[row] = s + bias2;
    }
  }
  if (c16 < 3) {
    const float bi = biw[0];
    #pragma unroll
    for (int r = 0; r < 4; ++r) {
      int row = row0 + 16 * w + 4 * q + r;
      int bb = row >> 9, ss = row & 511;
      int lab = plab[row];
      float wgt = (lab > 0) ? 1.f + bi : 1.f;
      float ev = (acc[4][r] + bpos[c16]) * wgt;
      em_t[(ss * 3 + c16) * 64 + bb] = ev;
      if (c16 == 0) labels_t[ss * 64 + bb] = lab;
    }
  }
}

// ---------------- K_F: fused {kd | k2a} + last-block CRF chunk-scan + combine ----------------
__global__ __launch_bounds__(256) void kf_fused(
    const float* __restrict__ hidden, const float* __restrict__ scores,
    const int* __restrict__ tpos, const int* __restrict__ tlab,
    const unsigned short* __restrict__ wt_type, const float* __restrict__ btype,
    const float* __restrict__ em_t, const int* __restrict__ labels_t,
    const int* __restrict__ lengths, const float* __restrict__ trans,
    const float* __restrict__ strans, const float* __restrict__ etrans,
    float* __restrict__ matM, float* __restrict__ psc, float* __restrict__ scal,
    float* __restrict__ out) {
  __shared__ int last_flag;
  const int bid = blockIdx.x;
  const int t = threadIdx.x, w = t >> 6, l = t & 63;

  if (bid >= 64) {
    // ---------------- k2a: chunk c, lane = sequence ----------------
    const int b = l, c = (bid - 64) * 4 + w;
    float T0 = trans[0], T1 = trans[1], T2 = trans[2];
    float T3 = trans[3], T4 = trans[4], T5 = trans[5];
    float T6 = trans[6], T7 = trans[7], T8 = trans[8];
    const int L = lengths[b];
    const int s0 = 8 * c;
    int labp = labels_t[(c ? (s0 - 1) : 0) * 64 + b];

    float E0[8], E1[8], E2[8]; int LB[8];
    #pragma unroll
    for (int i = 0; i < 8; ++i) {
      E0[i] = em_t[((s0 + i) * 3 + 0) * 64 + b];
      E1[i] = em_t[((s0 + i) * 3 + 1) * 64 + b];
      E2[i] = em_t[((s0 + i) * 3 + 2) * 64 + b];
      LB[i] = labels_t[(s0 + i) * 64 + b];
    }

    float M[9];
    #pragma unroll
    for (int i = 0; i < 9; ++i) M[i] = (i == 0 || i == 4 || i == 8) ? 0.f : NEGB;
    float sc = 0.f;

    #pragma unroll
    for (int i = 0; i < 8; ++i) {
      int s = s0 + i;
      bool act = (s >= 1) && (s < L);
      float N[9];
      #pragma unroll
      for (int r = 0; r < 3; ++r) {
        float ma = M[3 * r], mb = M[3 * r + 1], mc = M[3 * r + 2];
        N[3 * r + 0] = lse3(ma + T0, mb + T3, mc + T6) + E0[i];
        N[3 * r + 1] = lse3(ma + T1, mb + T4, mc + T7) + E1[i];
        N[3 * r + 2] = lse3(ma + T2, mb + T5, mc + T8) + E2[i];
      }
      #pragma unroll
      for (int r = 0; r < 9; ++r) M[r] = act ? N[r] : M[r];
      int lab = LB[i];
      float ev = sel3(E0[i], E1[i], E2[i], lab);
      float trv = sel3(sel3(T0, T1, T2, lab),
                       sel3(T3, T4, T5, lab),
                       sel3(T6, T7, T8, lab), labp);
      sc += act ? (ev + trv) : 0.f;
      labp = lab;
    }
    #pragma unroll
    for (int i = 0; i < 9; ++i) matM[(c * 9 + i) * 64 + b] = M[i];
    psc[c * 64 + b] = sc;
  } else {
    // ---------------- kd: batch bid, 8 spans ----------------
    __shared__ unsigned short Apool[8][776];
    __shared__ float red[4][8][3];
    __shared__ float vl[8];
    const int b = bid;

    {
      const int sp = t >> 5;
      const int span = b * 8 + sp;
      const int st = tpos[span * 2], en = tpos[span * 2 + 1];
      const int len = (st + en > 0) ? (en - st) : 0;
      float sv[7], aw[7];
      float wm = -1e30f;
      #pragma unroll
      for (int j = 0; j < 7; ++j) {
        sv[j] = (j < len) ? scores[b * 512 + st + j] : -1e30f;
        wm = fmaxf(wm, sv[j]);
      }
      float den = 0.f;
      #pragma unroll
      for (int j = 0; j < 7; ++j) {
        aw[j] = (j < len) ? exp2f((sv[j] - wm) * L2E) : 0.f;
        den += aw[j];
      }
      float inv = (den > 0.f) ? 1.f / den : 0.f;
      #pragma unroll
      for (int j = 0; j < 7; ++j) aw[j] *= inv;

      const int h0 = (t & 31) * 24;
      float ap[24];
      #pragma unroll
      for (int i = 0; i < 24; ++i) ap[i] = 0.f;
      #pragma unroll
      for (int j = 0; j < 7; ++j) {
        if (j < len) {
          const float4* hp = (const float4*)(hidden + (size_t)(b * 512 + st + j) * 768 + h0);
          #pragma unroll
          for (int i = 0; i < 6; ++i) {
            float4 v = hp[i];
            ap[4 * i + 0] += aw[j] * v.x; ap[4 * i + 1] += aw[j] * v.y;
            ap[4 * i + 2] += aw[j] * v.z; ap[4 * i + 3] += aw[j] * v.w;
          }
        }
      }
      unsigned short* dp = &Apool[sp][h0];
      #pragma unroll
      for (int g = 0; g < 3; ++g) {
        uint4 v;
        v.x = (unsigned)f2bf(ap[8 * g + 0]) | ((unsigned)f2bf(ap[8 * g + 1]) << 16);
        v.y = (unsigned)f2bf(ap[8 * g + 2]) | ((unsigned)f2bf(ap[8 * g + 3]) << 16);
        v.z = (unsigned)f2bf(ap[8 * g + 4]) | ((unsigned)f2bf(ap[8 * g + 5]) << 16);
        v.w = (unsigned)f2bf(ap[8 * g + 6]) | ((unsigned)f2bf(ap[8 * g + 7]) << 16);
        *(uint4*)(dp + 8 * g) = v;
      }
    }
    __syncthreads();

    f32x4 acc[8];
    #pragma unroll
    for (int nt = 0; nt < 8; ++nt) acc[nt] = (f32x4){0.f, 0.f, 0.f, 0.f};
    const int arow = l & 15;
    const bf16x8 zerov = (bf16x8)(__bf16)0.f;
    for (int ks = 0; ks < 24; ++ks) {
      bf16x8 a = (arow < 8) ? *(const bf16x8*)(&Apool[arow][ks * 32 + 8 * (l >> 4)]) : zerov;
      #pragma unroll
      for (int nt = 0; nt < 8; ++nt) {
        int col = 128 * w + 16 * nt + (l & 15);
        bf16x8 bb = *(const bf16x8*)(wt_type + (size_t)col * 768 + ks * 32 + 8 * (l >> 4));
        acc[nt] = __builtin_amdgcn_mfma_f32_16x16x32_bf16(a, bb, acc[nt], 0, 0, 0);
      }
    }

    float bt[8]; bool vc[8];
    #pragma unroll
    for (int nt = 0; nt < 8; ++nt) {
      int col = 128 * w + 16 * nt + (l & 15);
      vc[nt] = col < 500;
      bt[nt] = vc[nt] ? btype[col] : 0.f;
    }
    #pragma unroll
    for (int r = 0; r < 4; ++r) {
      float lmax = -1e30f, ssum = 0.f;
      #pragma unroll
      for (int nt = 0; nt < 8; ++nt) {
        float lv = vc[nt] ? (acc[nt][r] + bt[nt]) : -1e30f;
        lmax = fmaxf(lmax, lv);
        ssum += vc[nt] ? lv : 0.f;
      }
      #pragma unroll
      for (int off = 1; off < 16; off <<= 1) lmax = fmaxf(lmax, __shfl_xor(lmax, off, 64));
      float sexp = 0.f;
      #pragma unroll
      for (int nt = 0; nt < 8; ++nt) {
        float lv = vc[nt] ? (acc[nt][r] + bt[nt]) : -1e30f;
        sexp += vc[nt] ? exp2f((lv - lmax) * L2E) : 0.f;
      }
      #pragma unroll
      for (int off = 1; off < 16; off <<= 1) {
        sexp += __shfl_xor(sexp, off, 64);
        ssum += __shfl_xor(ssum, off, 64);
      }
      if ((l & 15) == 0 && (l >> 4) < 2) {
        int row = 4 * (l >> 4) + r;
        red[w][row][0] = lmax; red[w][row][1] = sexp; red[w][row][2] = ssum;
      }
      if ((l >> 4) < 2) {
        int row = 4 * (l >> 4) + r;
        int lbl = tlab[b * 8 + row];
        if ((lbl >> 7) == w && (lbl & 15) == (l & 15)) {
          #pragma unroll
          for (int nt = 0; nt < 8; ++nt)
            if (((lbl >> 4) & 7) == nt) vl[row] = acc[nt][r] + btype[lbl];
        }
      }
    }
    __syncthreads();

    float fv = 0.f, vv = 0.f;
    if (t < 8) {
      const int row = t;
      float gm = fmaxf(fmaxf(red[0][row][0], red[1][row][0]),
                       fmaxf(red[2][row][0], red[3][row][0]));
      float sexp = 0.f, ssum = 0.f;
      #pragma unroll
      for (int i = 0; i < 4; ++i) {
        sexp += red[i][row][1] * exp2f((red[i][row][0] - gm) * L2E);
        ssum += red[i][row][2];
      }
      float logZ = gm + log2f(sexp) * LN2;
      float lp = vl[row] - logZ;
      float ce = -(0.9f * lp + 2e-4f * (ssum - 500.f * logZ));
      float pt = 0.9f * exp2f(lp * L2E) + 2e-4f;
      float focal = ce * (1.f - pt) * (1.f - pt);
      int span = b * 8 + row;
      bool valid = (tpos[span * 2] + tpos[span * 2 + 1]) > 0;
      fv = valid ? focal : 0.f;
      vv = valid ? 1.f : 0.f;
    }
    #pragma unroll
    for (int off = 1; off < 8; off <<= 1) {
      fv += __shfl_xor(fv, off, 64);
      vv += __shfl_xor(vv, off, 64);
    }
    if (t == 0) {
      atomicAdd(&scal[1], fv);
      atomicAdd(&scal[2], vv);
    }
  }

  // ---------------- last-block: CRF chunk-scan (alpha over 64 chunk mats) + combine ----------
  __syncthreads();
  if (t == 0) {
    __threadfence();                                  // release this block's global stores
    unsigned old = atomicAdd((unsigned*)&scal[3], 1u);
    last_flag = (old == 79u);
  }
  __syncthreads();
  if (last_flag && t < 64) {
    __threadfence();                                  // acquire all blocks' stores
    const int b = t;
    const int L = lengths[b];
    const float st0 = strans[0], st1 = strans[1], st2 = strans[2];
    const float et0 = etrans[0], et1 = etrans[1], et2 = etrans[2];
    float e00 = em_t[0 * 64 + b], e01 = em_t[1 * 64 + b], e02 = em_t[2 * 64 + b];
    int lab0 = labels_t[b];
    float a0 = st0 + e00, a1 = st1 + e01, a2 = st2 + e02;
    float score = sel3(st0, st1, st2, lab0) + sel3(e00, e01, e02, lab0);

    float cur[4][10];
    #pragma unroll
    for (int j = 0; j < 4; ++j) {
      #pragma unroll
      for (int i = 0; i < 9; ++i) cur[j][i] = matM[(j * 9 + i) * 64 + b];
      cur[j][9] = psc[j * 64 + b];
    }
    for (int r = 0; r < 16; ++r) {
      float nxt[4][10];
      if (r < 15) {
        #pragma unroll
        for (int j = 0; j < 4; ++j) {
          int c = (r + 1) * 4 + j;
          #pragma unroll
          for (int i = 0; i < 9; ++i) nxt[j][i] = matM[(c * 9 + i) * 64 + b];
          nxt[j][9] = psc[c * 64 + b];
        }
      }
      #pragma unroll
      for (int j = 0; j < 4; ++j) {
        float n0 = lse3(a0 + cur[j][0], a1 + cur[j][3], a2 + cur[j][6]);
        float n1 = lse3(a0 + cur[j][1], a1 + cur[j][4], a2 + cur[j][7]);
        float n2 = lse3(a0 + cur[j][2], a1 + cur[j][5], a2 + cur[j][8]);
        a0 = n0; a1 = n1; a2 = n2;
        score += cur[j][9];
      }
      if (r < 15) {
        #pragma unroll
        for (int j = 0; j < 4; ++j)
          #pragma unroll
          for (int i = 0; i < 10; ++i) cur[j][i] = nxt[j][i];
      }
    }
    int last = labels_t[(L - 1) * 64 + b];
    score += sel3(et0, et1, et2, last);
    float logZ = lse3(a0 + et0, a1 + et1, a2 + et2);
    float nll = logZ - score;
    #pragma unroll
    for (int off = 1; off < 64; off <<= 1) nll += __shfl_xor(nll, off, 64);
    if (b == 0) {
      float pos = nll / 64.f;
      float type = scal[1] / fmaxf(scal[2], 1.f) * 10.f;
      out[0] = 0.6f * pos + 0.4f * type;
      out[1] = pos;
      out[2] = type;
    }
  }
}

extern "C" void kernel_launch(void* const* d_in, const int* in_sizes, int n_in,
                              void* d_out, int out_size, void* d_ws, size_t ws_size,
                              hipStream_t stream) {
  const float* hidden = (const float*)d_in[0];
  const int*   amask  = (const int*)d_in[1];
  const int*   plab   = (const int*)d_in[2];
  const int*   tlab   = (const int*)d_in[3];
  const int*   tpos   = (const int*)d_in[4];
  const float* biw    = (const float*)d_in[5];
  const float* Wpos   = (const float*)d_in[6];
  const float* bpos   = (const float*)d_in[7];
  const float* strans = (const float*)d_in[8];
  const float* etrans = (const float*)d_in[9];
  const float* trans  = (const float*)d_in[10];
  const float* W1     = (const float*)d_in[11];
  const float* b1     = (const float*)d_in[12];
  const float* W2     = (const float*)d_in[13];
  const float* b2     = (const float*)d_in[14];
  const float* Wtype  = (const float*)d_in[15];
  const float* btype  = (const float*)d_in[16];
  float* out = (float*)d_out;
  char* ws = (char*)d_ws;

  unsigned short* wt_all  = (unsigned short*)(ws + WT_ALL_OFF);
  unsigned short* wt_type = (unsigned short*)(ws + WT_TYPE_OFF);
  float* em_t    = (float*)(ws + EM_T_OFF);
  float* scores  = (float*)(ws + SCORES_OFF);
  int*   labelsT = (int*)(ws + LABELS_T_OFF);
  int*   lengths = (int*)(ws + LEN_OFF);
  float* scal    = (float*)(ws + SCAL_OFF);
  float* matM    = (float*)(ws + MATM_OFF);
  float* psc     = (float*)(ws + PSC_OFF);

  ka_prep<<<110, 256, 0, stream>>>(W1, Wpos, Wtype, amask, wt_all, wt_type, lengths, scal);
  k1_gemm<<<512, 256, 0, stream>>>(hidden, plab, bpos, b1, W2, b2, biw, wt_all,
                                   em_t, scores, labelsT);
  kf_fused<<<80, 256, 0, stream>>>(hidden, scores, tpos, tlab, wt_type, btype,
                                   em_t, labelsT, lengths, trans, strans, etrans,
                                   matM, psc, scal, out);
}